// Round 1
// baseline (26092.474 us; speedup 1.0000x reference)
//
#include <hip/hip_runtime.h>
#include <hip/hip_bf16.h>

// Multi-layer Elman RNN, persistent wavefront pipeline.
// SEQ=512, B=64, IN=H=512, L=4.  out[t][l][b][h] fp32.
//
// 256 WGs x 256 threads (1 per CU). WG -> (layer l, batch-group g of 16, H-chunk c of 32 rows).
// Weights held register-resident as bf16 MFMA fragments for the whole run.
// Waves split K=1024 4-ways; hi/lo bf16 A-operand split for ~fp32 input accuracy.
// Flag-based producer/consumer sync (device-scope atomics), 4-deep bf16 h-ring in ws.

#define SEQ    512
#define BATCH  64
#define HID    512
#define NL     4
#define NG     4
#define NCH    16
#define RSLOTS 4

typedef __attribute__((ext_vector_type(8))) short bf16x8;
typedef __attribute__((ext_vector_type(4))) float f32x4;

__device__ __forceinline__ short f2b(float f) {
  unsigned int u;
  __builtin_memcpy(&u, &f, 4);
  unsigned int r = (u + 0x7FFFu + ((u >> 16) & 1u)) >> 16;  // RNE
  return (short)r;
}
__device__ __forceinline__ float b2f(short s) {
  unsigned int u = ((unsigned int)(unsigned short)s) << 16;
  float f;
  __builtin_memcpy(&f, &u, 4);
  return f;
}
__device__ __forceinline__ float fast_tanh(float v) {
  v = fminf(10.0f, fmaxf(-10.0f, v));
  float e = __expf(2.0f * v);
  return 1.0f - 2.0f * __builtin_amdgcn_rcpf(e + 1.0f);
}
__device__ __forceinline__ void spin_until(int* p, int tgt) {
  if (tgt <= 0) return;
  long guard = 0;
  while (__hip_atomic_load(p, __ATOMIC_ACQUIRE, __HIP_MEMORY_SCOPE_AGENT) < tgt) {
    __builtin_amdgcn_s_sleep(2);
    if (++guard > 50000000L) break;  // failsafe against hang
  }
}
__device__ __forceinline__ void split8v(const float4 p0, const float4 p1,
                                        bf16x8& hi, bf16x8& lo) {
  float f[8] = {p0.x, p0.y, p0.z, p0.w, p1.x, p1.y, p1.z, p1.w};
  #pragma unroll
  for (int q = 0; q < 8; ++q) {
    short h = f2b(f[q]);
    hi[q] = h;
    lo[q] = f2b(f[q] - b2f(h));
  }
}

__global__ __launch_bounds__(256, 1) void rnn_wavefront(
    const float* __restrict__ x,
    const float* __restrict__ Wih,
    const float* __restrict__ Whh,
    const float* __restrict__ bih,
    const float* __restrict__ bhh,
    float* __restrict__ out,
    short* __restrict__ ring_hi,
    short* __restrict__ ring_lo,
    int* done)
{
  const int tid  = threadIdx.x;
  const int wave = tid >> 6;
  const int lane = tid & 63;
  const int fr   = lane & 15;   // frag 16-dim index
  const int kq   = lane >> 4;   // frag k-quad
  const int wg   = blockIdx.x;
  const int cell = wg >> 4;     // 0..15 = l*NG+g
  const int l    = cell >> 2;
  const int g    = cell & 3;
  const int c    = wg & 15;     // 32-row H chunk

  __shared__ float red[4 * 512];  // [wave][nt*256 + i*16 + j]

  // ---- persistent register weights: rows n = c*32+nt*16+fr, k = wave*256.. ----
  bf16x8 wfrag[2][8];
  #pragma unroll
  for (int nt = 0; nt < 2; ++nt) {
    const int n = c * 32 + nt * 16 + fr;
    #pragma unroll
    for (int kt = 0; kt < 8; ++kt) {
      const int k = wave * 256 + kt * 32 + kq * 8;
      const float* src = (k < 512)
          ? Wih + ((size_t)l * HID + n) * 512 + k
          : Whh + ((size_t)l * HID + n) * 512 + (k - 512);
      float4 p0 = *(const float4*)src;
      float4 p1 = *(const float4*)(src + 4);
      bf16x8 w;
      w[0] = f2b(p0.x); w[1] = f2b(p0.y); w[2] = f2b(p0.z); w[3] = f2b(p0.w);
      w[4] = f2b(p1.x); w[5] = f2b(p1.y); w[6] = f2b(p1.z); w[7] = f2b(p1.w);
      wfrag[nt][kt] = w;
    }
  }

  // epilogue constants: thread -> (batch i, col j), two n's (nt=0,1)
  const int ei = tid >> 4;
  const int ej = tid & 15;
  const int bg = g * 16 + ei;
  const int n0 = c * 32 + ej;
  const int n1 = n0 + 16;
  const float bias0 = bih[l * HID + n0] + bhh[l * HID + n0];
  const float bias1 = bih[l * HID + n1] + bhh[l * HID + n1];

  const int brow = g * 16 + fr;  // A-frag batch row
  int* myDone = done + cell;

  for (int t = 0; t < SEQ; ++t) {
    // ---- flag waits: own h(t-1), upstream h_{l-1}(t), downstream back-pressure ----
    if (tid == 0) {
      spin_until(myDone, t * NCH);
      if (l > 0) spin_until(done + (cell - NG), (t + 1) * NCH);
      if (l < NL - 1 && t >= RSLOTS) spin_until(done + (cell + NG), (t - (RSLOTS - 1)) * NCH);
    }
    __syncthreads();

    f32x4 acc0 = {0.f, 0.f, 0.f, 0.f};
    f32x4 acc1 = {0.f, 0.f, 0.f, 0.f};
    const bool hside = (wave >= 2);
    if (!(hside && t == 0)) {          // h(-1) == 0: skip recurrent half at t=0
      bf16x8 ah[8], al[8];
      if (!hside && l == 0) {
        const float* xs = x + ((size_t)t * BATCH + brow) * 512 + wave * 256 + kq * 8;
        #pragma unroll
        for (int kt = 0; kt < 8; ++kt) {
          float4 p0 = *(const float4*)(xs + kt * 32);
          float4 p1 = *(const float4*)(xs + kt * 32 + 4);
          split8v(p0, p1, ah[kt], al[kt]);
        }
      } else {
        size_t base;
        if (!hside)
          base = (((size_t)(t & 3) * NL + (l - 1)) * BATCH + brow) * 512 + wave * 256 + kq * 8;
        else
          base = (((size_t)((t - 1) & 3) * NL + l) * BATCH + brow) * 512 + (wave - 2) * 256 + kq * 8;
        const short* ph = ring_hi + base;
        const short* pl = ring_lo + base;
        #pragma unroll
        for (int kt = 0; kt < 8; ++kt) {
          ah[kt] = *(const bf16x8*)(ph + kt * 32);
          al[kt] = *(const bf16x8*)(pl + kt * 32);
        }
      }
      #pragma unroll
      for (int kt = 0; kt < 8; ++kt) {
        acc0 = __builtin_amdgcn_mfma_f32_16x16x32_bf16(ah[kt], wfrag[0][kt], acc0, 0, 0, 0);
        acc1 = __builtin_amdgcn_mfma_f32_16x16x32_bf16(ah[kt], wfrag[1][kt], acc1, 0, 0, 0);
        acc0 = __builtin_amdgcn_mfma_f32_16x16x32_bf16(al[kt], wfrag[0][kt], acc0, 0, 0, 0);
        acc1 = __builtin_amdgcn_mfma_f32_16x16x32_bf16(al[kt], wfrag[1][kt], acc1, 0, 0, 0);
      }
    }

    // ---- K-split reduction across waves via LDS ----
    {
      float* pw = red + wave * 512;
      #pragma unroll
      for (int r = 0; r < 4; ++r) {
        pw[(kq * 4 + r) * 16 + fr]       = acc0[r];   // C layout: row i=(lane>>4)*4+r, col j=lane&15
        pw[256 + (kq * 4 + r) * 16 + fr] = acc1[r];
      }
    }
    __syncthreads();

    {
      float v0 = red[tid] + red[512 + tid] + red[1024 + tid] + red[1536 + tid] + bias0;
      float v1 = red[256 + tid] + red[768 + tid] + red[1280 + tid] + red[1792 + tid] + bias1;
      float th0 = fast_tanh(v0);
      float th1 = fast_tanh(v1);
      size_t o = (((size_t)t * NL + l) * BATCH + bg) * 512;
      out[o + n0] = th0;
      out[o + n1] = th1;
      size_t rb = (((size_t)(t & 3) * NL + l) * BATCH + bg) * 512;
      short h0 = f2b(th0);
      short h1 = f2b(th1);
      ring_hi[rb + n0] = h0;
      ring_hi[rb + n1] = h1;
      ring_lo[rb + n0] = f2b(th0 - b2f(h0));
      ring_lo[rb + n1] = f2b(th1 - b2f(h1));
    }
    __threadfence();
    __syncthreads();
    if (tid == 0)
      __hip_atomic_fetch_add(myDone, 1, __ATOMIC_RELEASE, __HIP_MEMORY_SCOPE_AGENT);
  }
}

extern "C" void kernel_launch(void* const* d_in, const int* in_sizes, int n_in,
                              void* d_out, int out_size, void* d_ws, size_t ws_size,
                              hipStream_t stream) {
  (void)in_sizes; (void)n_in; (void)out_size; (void)ws_size;
  const float* x   = (const float*)d_in[0];
  const float* Wih = (const float*)d_in[1];
  const float* Whh = (const float*)d_in[2];
  const float* bih = (const float*)d_in[3];
  const float* bhh = (const float*)d_in[4];
  float* out = (float*)d_out;

  const size_t ringElems = (size_t)RSLOTS * NL * BATCH * HID;  // 524288
  short* ring_hi = (short*)d_ws;
  short* ring_lo = ring_hi + ringElems;
  int* done = (int*)(ring_lo + ringElems);   // ws is poisoned 0xAA -> must zero flags

  hipMemsetAsync(done, 0, (NL * NG) * sizeof(int), stream);
  rnn_wavefront<<<dim3(256), dim3(256), 0, stream>>>(x, Wih, Whh, bih, bhh, out,
                                                     ring_hi, ring_lo, done);
}

// Round 2
// 10019.080 us; speedup vs baseline: 2.6043x; 2.6043x over previous
//
#include <hip/hip_runtime.h>
#include <hip/hip_bf16.h>

// Multi-layer Elman RNN, persistent wavefront pipeline — R2.
// Change vs R1: eliminate ALL cache-maintenance ops (buffer_wbl2 / buffer_inv).
// Cross-WG h-ring uses explicit sc0+sc1 (coherence-point) loads/stores via inline
// asm; flags are RELAXED agent atomics; ordering via s_waitcnt vmcnt(0) +
// control dependence. Ring packs hi/lo bf16 into one uint per element.

#define SEQ    512
#define BATCH  64
#define HID    512
#define NL     4
#define NG     4
#define NCH    16
#define RSLOTS 4

typedef __attribute__((ext_vector_type(8))) short bf16x8;
typedef __attribute__((ext_vector_type(4))) float f32x4;
typedef __attribute__((ext_vector_type(4))) unsigned int u32x4;

__device__ __forceinline__ short f2b(float f) {
  unsigned int u;
  __builtin_memcpy(&u, &f, 4);
  unsigned int r = (u + 0x7FFFu + ((u >> 16) & 1u)) >> 16;  // RNE
  return (short)r;
}
__device__ __forceinline__ float b2f(short s) {
  unsigned int u = ((unsigned int)(unsigned short)s) << 16;
  float f;
  __builtin_memcpy(&f, &u, 4);
  return f;
}
__device__ __forceinline__ float fast_tanh(float v) {
  v = fminf(10.0f, fmaxf(-10.0f, v));
  float e = __expf(2.0f * v);
  return 1.0f - 2.0f * __builtin_amdgcn_rcpf(e + 1.0f);
}
// RELAXED spin — no buffer_inv per iteration.
__device__ __forceinline__ void spin_until(int* p, int tgt) {
  long guard = 0;
  while (__hip_atomic_load(p, __ATOMIC_RELAXED, __HIP_MEMORY_SCOPE_AGENT) < tgt) {
    __builtin_amdgcn_s_sleep(1);
    if (++guard > 100000000L) break;  // failsafe against hang
  }
}
__device__ __forceinline__ void split8v(const float4 p0, const float4 p1,
                                        bf16x8& hi, bf16x8& lo) {
  float f[8] = {p0.x, p0.y, p0.z, p0.w, p1.x, p1.y, p1.z, p1.w};
  #pragma unroll
  for (int q = 0; q < 8; ++q) {
    short h = f2b(f[q]);
    hi[q] = h;
    lo[q] = f2b(f[q] - b2f(h));
  }
}
// Coherence-point store of one packed uint (no L2 writeback needed later).
__device__ __forceinline__ void store_coh(unsigned int* p, unsigned int v) {
  asm volatile("global_store_dword %0, %1, off sc0 sc1" :: "v"(p), "v"(v) : "memory");
}

__global__ __launch_bounds__(256, 1) void rnn_wavefront(
    const float* __restrict__ x,
    const float* __restrict__ Wih,
    const float* __restrict__ Whh,
    const float* __restrict__ bih,
    const float* __restrict__ bhh,
    float* __restrict__ out,
    unsigned int* __restrict__ ring,   // [RSLOTS][NL][BATCH][HID] packed hi|lo bf16
    int* done)
{
  const int tid  = threadIdx.x;
  const int wave = tid >> 6;
  const int lane = tid & 63;
  const int fr   = lane & 15;   // frag 16-dim index
  const int kq   = lane >> 4;   // frag k-quad
  const int wg   = blockIdx.x;
  const int cell = wg >> 4;     // 0..15 = l*NG+g
  const int l    = cell >> 2;
  const int g    = cell & 3;
  const int c    = wg & 15;     // 32-row H chunk

  __shared__ float red[4 * 512];  // [wave][nt*256 + i*16 + j]

  // ---- persistent register weights: rows n = c*32+nt*16+fr, k = wave*256.. ----
  bf16x8 wfrag[2][8];
  #pragma unroll
  for (int nt = 0; nt < 2; ++nt) {
    const int n = c * 32 + nt * 16 + fr;
    #pragma unroll
    for (int kt = 0; kt < 8; ++kt) {
      const int k = wave * 256 + kt * 32 + kq * 8;
      const float* src = (k < 512)
          ? Wih + ((size_t)l * HID + n) * 512 + k
          : Whh + ((size_t)l * HID + n) * 512 + (k - 512);
      float4 p0 = *(const float4*)src;
      float4 p1 = *(const float4*)(src + 4);
      bf16x8 w;
      w[0] = f2b(p0.x); w[1] = f2b(p0.y); w[2] = f2b(p0.z); w[3] = f2b(p0.w);
      w[4] = f2b(p1.x); w[5] = f2b(p1.y); w[6] = f2b(p1.z); w[7] = f2b(p1.w);
      wfrag[nt][kt] = w;
    }
  }

  // epilogue constants: thread -> (batch i, col j), two n's (nt=0,1)
  const int ei = tid >> 4;
  const int ej = tid & 15;
  const int bg = g * 16 + ei;
  const int n0 = c * 32 + ej;
  const int n1 = n0 + 16;
  const float bias0 = bih[l * HID + n0] + bhh[l * HID + n0];
  const float bias1 = bih[l * HID + n1] + bhh[l * HID + n1];

  const int brow = g * 16 + fr;  // A-frag batch row
  int* myDone = done + cell;
  const bool hside = (wave >= 2);
  const int wv = wave & 1;       // K half-slice within side

  for (int t = 0; t < SEQ; ++t) {
    // ---- per-wave flag waits (relaxed; no cache maintenance) ----
    if (wave == 0) {
      if (l > 0) spin_until(done + (cell - NG), (t + 1) * NCH);
      if (l < NL - 1 && t >= RSLOTS) spin_until(done + (cell + NG), (t - (RSLOTS - 1)) * NCH);
    } else if (wave == 1) {
      if (l > 0) spin_until(done + (cell - NG), (t + 1) * NCH);
    } else {
      if (t > 0) spin_until(myDone, t * NCH);
    }

    f32x4 acc0 = {0.f, 0.f, 0.f, 0.f};
    f32x4 acc1 = {0.f, 0.f, 0.f, 0.f};
    if (!(hside && t == 0)) {          // h(-1) == 0: skip recurrent half at t=0
      bf16x8 ah[8], al[8];
      if (!hside && l == 0) {
        const float* xs = x + ((size_t)t * BATCH + brow) * 512 + wave * 256 + kq * 8;
        #pragma unroll
        for (int kt = 0; kt < 8; ++kt) {
          float4 p0 = *(const float4*)(xs + kt * 32);
          float4 p1 = *(const float4*)(xs + kt * 32 + 4);
          split8v(p0, p1, ah[kt], al[kt]);
        }
      } else {
        const int slot = hside ? ((t - 1) & 3) : (t & 3);
        const int lsrc = hside ? l : (l - 1);
        const unsigned int* base =
            ring + (((size_t)slot * NL + lsrc) * BATCH + brow) * HID + wv * 256 + kq * 8;
        u32x4 r[16];
        asm volatile(
            "global_load_dwordx4 %0,  %16, off offset:0   sc0 sc1\n\t"
            "global_load_dwordx4 %1,  %16, off offset:16  sc0 sc1\n\t"
            "global_load_dwordx4 %2,  %16, off offset:128 sc0 sc1\n\t"
            "global_load_dwordx4 %3,  %16, off offset:144 sc0 sc1\n\t"
            "global_load_dwordx4 %4,  %16, off offset:256 sc0 sc1\n\t"
            "global_load_dwordx4 %5,  %16, off offset:272 sc0 sc1\n\t"
            "global_load_dwordx4 %6,  %16, off offset:384 sc0 sc1\n\t"
            "global_load_dwordx4 %7,  %16, off offset:400 sc0 sc1\n\t"
            "global_load_dwordx4 %8,  %16, off offset:512 sc0 sc1\n\t"
            "global_load_dwordx4 %9,  %16, off offset:528 sc0 sc1\n\t"
            "global_load_dwordx4 %10, %16, off offset:640 sc0 sc1\n\t"
            "global_load_dwordx4 %11, %16, off offset:656 sc0 sc1\n\t"
            "global_load_dwordx4 %12, %16, off offset:768 sc0 sc1\n\t"
            "global_load_dwordx4 %13, %16, off offset:784 sc0 sc1\n\t"
            "global_load_dwordx4 %14, %16, off offset:896 sc0 sc1\n\t"
            "global_load_dwordx4 %15, %16, off offset:912 sc0 sc1\n\t"
            "s_waitcnt vmcnt(0)"
            : "=&v"(r[0]), "=&v"(r[1]), "=&v"(r[2]), "=&v"(r[3]),
              "=&v"(r[4]), "=&v"(r[5]), "=&v"(r[6]), "=&v"(r[7]),
              "=&v"(r[8]), "=&v"(r[9]), "=&v"(r[10]), "=&v"(r[11]),
              "=&v"(r[12]), "=&v"(r[13]), "=&v"(r[14]), "=&v"(r[15])
            : "v"(base)
            : "memory");
        #pragma unroll
        for (int kt = 0; kt < 8; ++kt) {
          bf16x8 h8, l8;
          #pragma unroll
          for (int j = 0; j < 4; ++j) {
            unsigned int ua = r[2 * kt][j];
            unsigned int ub = r[2 * kt + 1][j];
            h8[j]     = (short)(ua >> 16);
            l8[j]     = (short)(ua & 0xffffu);
            h8[j + 4] = (short)(ub >> 16);
            l8[j + 4] = (short)(ub & 0xffffu);
          }
          ah[kt] = h8;
          al[kt] = l8;
        }
      }
      #pragma unroll
      for (int kt = 0; kt < 8; ++kt) {
        acc0 = __builtin_amdgcn_mfma_f32_16x16x32_bf16(ah[kt], wfrag[0][kt], acc0, 0, 0, 0);
        acc1 = __builtin_amdgcn_mfma_f32_16x16x32_bf16(ah[kt], wfrag[1][kt], acc1, 0, 0, 0);
        acc0 = __builtin_amdgcn_mfma_f32_16x16x32_bf16(al[kt], wfrag[0][kt], acc0, 0, 0, 0);
        acc1 = __builtin_amdgcn_mfma_f32_16x16x32_bf16(al[kt], wfrag[1][kt], acc1, 0, 0, 0);
      }
    }

    // ---- K-split reduction across waves via LDS ----
    {
      float* pw = red + wave * 512;
      #pragma unroll
      for (int r = 0; r < 4; ++r) {
        pw[(kq * 4 + r) * 16 + fr]       = acc0[r];   // C layout: row i=(lane>>4)*4+r, col j=lane&15
        pw[256 + (kq * 4 + r) * 16 + fr] = acc1[r];
      }
    }
    __syncthreads();

    {
      float v0 = red[tid] + red[512 + tid] + red[1024 + tid] + red[1536 + tid] + bias0;
      float v1 = red[256 + tid] + red[768 + tid] + red[1280 + tid] + red[1792 + tid] + bias1;
      float th0 = fast_tanh(v0);
      float th1 = fast_tanh(v1);
      size_t o = (((size_t)t * NL + l) * BATCH + bg) * 512;
      out[o + n0] = th0;
      out[o + n1] = th1;
      size_t rb = (((size_t)(t & 3) * NL + l) * BATCH + bg) * 512;
      short h0 = f2b(th0), h1 = f2b(th1);
      unsigned int u0 = (((unsigned int)(unsigned short)h0) << 16) |
                        (unsigned int)(unsigned short)f2b(th0 - b2f(h0));
      unsigned int u1 = (((unsigned int)(unsigned short)h1) << 16) |
                        (unsigned int)(unsigned short)f2b(th1 - b2f(h1));
      store_coh(ring + rb + n0, u0);
      store_coh(ring + rb + n1, u1);
    }
    asm volatile("s_waitcnt vmcnt(0)" ::: "memory");  // ring stores at coherence point
    __syncthreads();                                   // whole WG's stores drained
    if (tid == 0)
      __hip_atomic_fetch_add(myDone, 1, __ATOMIC_RELAXED, __HIP_MEMORY_SCOPE_AGENT);
  }
}

extern "C" void kernel_launch(void* const* d_in, const int* in_sizes, int n_in,
                              void* d_out, int out_size, void* d_ws, size_t ws_size,
                              hipStream_t stream) {
  (void)in_sizes; (void)n_in; (void)out_size; (void)ws_size;
  const float* x   = (const float*)d_in[0];
  const float* Wih = (const float*)d_in[1];
  const float* Whh = (const float*)d_in[2];
  const float* bih = (const float*)d_in[3];
  const float* bhh = (const float*)d_in[4];
  float* out = (float*)d_out;

  const size_t ringElems = (size_t)RSLOTS * NL * BATCH * HID;  // 524288 uints = 2 MB
  unsigned int* ring = (unsigned int*)d_ws;
  int* done = (int*)(ring + ringElems);   // ws is poisoned 0xAA -> must zero flags

  hipMemsetAsync(done, 0, (NL * NG) * sizeof(int), stream);
  rnn_wavefront<<<dim3(256), dim3(256), 0, stream>>>(x, Wih, Whh, bih, bhh, out,
                                                     ring, done);
}

// Round 3
// 2338.559 us; speedup vs baseline: 11.1575x; 4.2843x over previous
//
#include <hip/hip_runtime.h>
#include <hip/hip_bf16.h>

// Multi-layer Elman RNN, persistent wavefront pipeline — R3.
// vs R2: (1) per-cell flag counters padded to own 128B line; (2) only one wave
// polls each global flag, siblings wait on an LDS mailbox; (3) fp32 out-stores
// issued AFTER the flag signal (off the critical cycle).

#define SEQ    512
#define BATCH  64
#define HID    512
#define NL     4
#define NG     4
#define NCH    16
#define RSLOTS 4
#define FLSTR  32   // ints per flag slot (128 B padding)

typedef __attribute__((ext_vector_type(8))) short bf16x8;
typedef __attribute__((ext_vector_type(4))) float f32x4;
typedef __attribute__((ext_vector_type(4))) unsigned int u32x4;

__device__ __forceinline__ short f2b(float f) {
  unsigned int u;
  __builtin_memcpy(&u, &f, 4);
  unsigned int r = (u + 0x7FFFu + ((u >> 16) & 1u)) >> 16;  // RNE
  return (short)r;
}
__device__ __forceinline__ float b2f(short s) {
  unsigned int u = ((unsigned int)(unsigned short)s) << 16;
  float f;
  __builtin_memcpy(&f, &u, 4);
  return f;
}
__device__ __forceinline__ float fast_tanh(float v) {
  v = fminf(10.0f, fmaxf(-10.0f, v));
  float e = __expf(2.0f * v);
  return 1.0f - 2.0f * __builtin_amdgcn_rcpf(e + 1.0f);
}
// RELAXED global spin — no cache maintenance per iteration.
__device__ __forceinline__ void spin_until(int* p, int tgt) {
  long guard = 0;
  while (__hip_atomic_load(p, __ATOMIC_RELAXED, __HIP_MEMORY_SCOPE_AGENT) < tgt) {
    __builtin_amdgcn_s_sleep(2);
    if (++guard > 100000000L) break;  // failsafe against hang
  }
}
// LDS mailbox spin (no global traffic).
__device__ __forceinline__ void lds_spin(volatile int* p, int tgt) {
  long guard = 0;
  while (*p < tgt) {
    __builtin_amdgcn_s_sleep(1);
    if (++guard > 400000000L) break;
  }
}
__device__ __forceinline__ void split8v(const float4 p0, const float4 p1,
                                        bf16x8& hi, bf16x8& lo) {
  float f[8] = {p0.x, p0.y, p0.z, p0.w, p1.x, p1.y, p1.z, p1.w};
  #pragma unroll
  for (int q = 0; q < 8; ++q) {
    short h = f2b(f[q]);
    hi[q] = h;
    lo[q] = f2b(f[q] - b2f(h));
  }
}
// Coherence-point store of one packed uint.
__device__ __forceinline__ void store_coh(unsigned int* p, unsigned int v) {
  asm volatile("global_store_dword %0, %1, off sc0 sc1" :: "v"(p), "v"(v) : "memory");
}

__global__ __launch_bounds__(256, 1) void rnn_wavefront(
    const float* __restrict__ x,
    const float* __restrict__ Wih,
    const float* __restrict__ Whh,
    const float* __restrict__ bih,
    const float* __restrict__ bhh,
    float* __restrict__ out,
    unsigned int* __restrict__ ring,   // [RSLOTS][NL][BATCH][HID] packed hi|lo bf16
    int* done)                          // [16] counters, stride FLSTR ints
{
  const int tid  = threadIdx.x;
  const int wave = tid >> 6;
  const int lane = tid & 63;
  const int fr   = lane & 15;   // frag 16-dim index
  const int kq   = lane >> 4;   // frag k-quad
  const int wg   = blockIdx.x;
  const int cell = wg >> 4;     // 0..15 = l*NG+g
  const int l    = cell >> 2;
  const int g    = cell & 3;
  const int c    = wg & 15;     // 32-row H chunk

  __shared__ float red[4 * 512];  // [wave][nt*256 + i*16 + j]
  __shared__ int mb_up, mb_rec;   // LDS mailboxes

  if (tid == 0) { mb_up = 0; mb_rec = 0; }

  // ---- persistent register weights: rows n = c*32+nt*16+fr, k = wave*256.. ----
  bf16x8 wfrag[2][8];
  #pragma unroll
  for (int nt = 0; nt < 2; ++nt) {
    const int n = c * 32 + nt * 16 + fr;
    #pragma unroll
    for (int kt = 0; kt < 8; ++kt) {
      const int k = wave * 256 + kt * 32 + kq * 8;
      const float* src = (k < 512)
          ? Wih + ((size_t)l * HID + n) * 512 + k
          : Whh + ((size_t)l * HID + n) * 512 + (k - 512);
      float4 p0 = *(const float4*)src;
      float4 p1 = *(const float4*)(src + 4);
      bf16x8 w;
      w[0] = f2b(p0.x); w[1] = f2b(p0.y); w[2] = f2b(p0.z); w[3] = f2b(p0.w);
      w[4] = f2b(p1.x); w[5] = f2b(p1.y); w[6] = f2b(p1.z); w[7] = f2b(p1.w);
      wfrag[nt][kt] = w;
    }
  }

  // epilogue constants: thread -> (batch i, col j), two n's (nt=0,1)
  const int ei = tid >> 4;
  const int ej = tid & 15;
  const int bg = g * 16 + ei;
  const int n0 = c * 32 + ej;
  const int n1 = n0 + 16;
  const float bias0 = bih[l * HID + n0] + bhh[l * HID + n0];
  const float bias1 = bih[l * HID + n1] + bhh[l * HID + n1];

  const int brow = g * 16 + fr;  // A-frag batch row
  int* myDone = done + cell * FLSTR;
  const bool hside = (wave >= 2);
  const int wv = wave & 1;       // K half-slice within side

  __syncthreads();               // mailbox init visible

  for (int t = 0; t < SEQ; ++t) {
    // ---- flag waits: one polling wave per dependency, siblings on LDS ----
    if (wave == 0) {
      if (l > 0) {
        spin_until(done + (cell - NG) * FLSTR, (t + 1) * NCH);
        __hip_atomic_store(&mb_up, t + 1, __ATOMIC_RELEASE, __HIP_MEMORY_SCOPE_WORKGROUP);
      }
      if (l < NL - 1 && t >= RSLOTS)
        spin_until(done + (cell + NG) * FLSTR, (t - (RSLOTS - 1)) * NCH);
    } else if (wave == 1) {
      if (l > 0) lds_spin(&mb_up, t + 1);
    } else if (wave == 2) {
      if (t > 0) {
        spin_until(myDone, t * NCH);
        __hip_atomic_store(&mb_rec, t, __ATOMIC_RELEASE, __HIP_MEMORY_SCOPE_WORKGROUP);
      }
    } else {
      if (t > 0) lds_spin(&mb_rec, t);
    }

    f32x4 acc0 = {0.f, 0.f, 0.f, 0.f};
    f32x4 acc1 = {0.f, 0.f, 0.f, 0.f};
    if (!(hside && t == 0)) {          // h(-1) == 0: skip recurrent half at t=0
      bf16x8 ah[8], al[8];
      if (!hside && l == 0) {
        const float* xs = x + ((size_t)t * BATCH + brow) * 512 + wave * 256 + kq * 8;
        #pragma unroll
        for (int kt = 0; kt < 8; ++kt) {
          float4 p0 = *(const float4*)(xs + kt * 32);
          float4 p1 = *(const float4*)(xs + kt * 32 + 4);
          split8v(p0, p1, ah[kt], al[kt]);
        }
      } else {
        const int slot = hside ? ((t - 1) & 3) : (t & 3);
        const int lsrc = hside ? l : (l - 1);
        const unsigned int* base =
            ring + (((size_t)slot * NL + lsrc) * BATCH + brow) * HID + wv * 256 + kq * 8;
        u32x4 r[16];
        asm volatile(
            "global_load_dwordx4 %0,  %16, off offset:0   sc0 sc1\n\t"
            "global_load_dwordx4 %1,  %16, off offset:16  sc0 sc1\n\t"
            "global_load_dwordx4 %2,  %16, off offset:128 sc0 sc1\n\t"
            "global_load_dwordx4 %3,  %16, off offset:144 sc0 sc1\n\t"
            "global_load_dwordx4 %4,  %16, off offset:256 sc0 sc1\n\t"
            "global_load_dwordx4 %5,  %16, off offset:272 sc0 sc1\n\t"
            "global_load_dwordx4 %6,  %16, off offset:384 sc0 sc1\n\t"
            "global_load_dwordx4 %7,  %16, off offset:400 sc0 sc1\n\t"
            "global_load_dwordx4 %8,  %16, off offset:512 sc0 sc1\n\t"
            "global_load_dwordx4 %9,  %16, off offset:528 sc0 sc1\n\t"
            "global_load_dwordx4 %10, %16, off offset:640 sc0 sc1\n\t"
            "global_load_dwordx4 %11, %16, off offset:656 sc0 sc1\n\t"
            "global_load_dwordx4 %12, %16, off offset:768 sc0 sc1\n\t"
            "global_load_dwordx4 %13, %16, off offset:784 sc0 sc1\n\t"
            "global_load_dwordx4 %14, %16, off offset:896 sc0 sc1\n\t"
            "global_load_dwordx4 %15, %16, off offset:912 sc0 sc1\n\t"
            "s_waitcnt vmcnt(0)"
            : "=&v"(r[0]), "=&v"(r[1]), "=&v"(r[2]), "=&v"(r[3]),
              "=&v"(r[4]), "=&v"(r[5]), "=&v"(r[6]), "=&v"(r[7]),
              "=&v"(r[8]), "=&v"(r[9]), "=&v"(r[10]), "=&v"(r[11]),
              "=&v"(r[12]), "=&v"(r[13]), "=&v"(r[14]), "=&v"(r[15])
            : "v"(base)
            : "memory");
        #pragma unroll
        for (int kt = 0; kt < 8; ++kt) {
          bf16x8 h8, l8;
          #pragma unroll
          for (int j = 0; j < 4; ++j) {
            unsigned int ua = r[2 * kt][j];
            unsigned int ub = r[2 * kt + 1][j];
            h8[j]     = (short)(ua >> 16);
            l8[j]     = (short)(ua & 0xffffu);
            h8[j + 4] = (short)(ub >> 16);
            l8[j + 4] = (short)(ub & 0xffffu);
          }
          ah[kt] = h8;
          al[kt] = l8;
        }
      }
      #pragma unroll
      for (int kt = 0; kt < 8; ++kt) {
        acc0 = __builtin_amdgcn_mfma_f32_16x16x32_bf16(ah[kt], wfrag[0][kt], acc0, 0, 0, 0);
        acc1 = __builtin_amdgcn_mfma_f32_16x16x32_bf16(ah[kt], wfrag[1][kt], acc1, 0, 0, 0);
        acc0 = __builtin_amdgcn_mfma_f32_16x16x32_bf16(al[kt], wfrag[0][kt], acc0, 0, 0, 0);
        acc1 = __builtin_amdgcn_mfma_f32_16x16x32_bf16(al[kt], wfrag[1][kt], acc1, 0, 0, 0);
      }
    }

    // ---- K-split reduction across waves via LDS ----
    {
      float* pw = red + wave * 512;
      #pragma unroll
      for (int r = 0; r < 4; ++r) {
        pw[(kq * 4 + r) * 16 + fr]       = acc0[r];   // C layout: row i=(lane>>4)*4+r, col j=lane&15
        pw[256 + (kq * 4 + r) * 16 + fr] = acc1[r];
      }
    }
    __syncthreads();

    float th0, th1;
    {
      float v0 = red[tid] + red[512 + tid] + red[1024 + tid] + red[1536 + tid] + bias0;
      float v1 = red[256 + tid] + red[768 + tid] + red[1280 + tid] + red[1792 + tid] + bias1;
      th0 = fast_tanh(v0);
      th1 = fast_tanh(v1);
      size_t rb = (((size_t)(t & 3) * NL + l) * BATCH + bg) * 512;
      short h0 = f2b(th0), h1 = f2b(th1);
      unsigned int u0 = (((unsigned int)(unsigned short)h0) << 16) |
                        (unsigned int)(unsigned short)f2b(th0 - b2f(h0));
      unsigned int u1 = (((unsigned int)(unsigned short)h1) << 16) |
                        (unsigned int)(unsigned short)f2b(th1 - b2f(h1));
      store_coh(ring + rb + n0, u0);
      store_coh(ring + rb + n1, u1);
    }
    asm volatile("s_waitcnt vmcnt(0)" ::: "memory");  // ring stores at coherence point
    __syncthreads();                                   // whole WG's stores drained
    if (tid == 0)
      __hip_atomic_fetch_add(myDone, 1, __ATOMIC_RELAXED, __HIP_MEMORY_SCOPE_AGENT);

    // fp32 output stores AFTER the signal — off the critical cycle
    {
      size_t o = (((size_t)t * NL + l) * BATCH + bg) * 512;
      out[o + n0] = th0;
      out[o + n1] = th1;
    }
  }
}

extern "C" void kernel_launch(void* const* d_in, const int* in_sizes, int n_in,
                              void* d_out, int out_size, void* d_ws, size_t ws_size,
                              hipStream_t stream) {
  (void)in_sizes; (void)n_in; (void)out_size; (void)ws_size;
  const float* x   = (const float*)d_in[0];
  const float* Wih = (const float*)d_in[1];
  const float* Whh = (const float*)d_in[2];
  const float* bih = (const float*)d_in[3];
  const float* bhh = (const float*)d_in[4];
  float* out = (float*)d_out;

  const size_t ringElems = (size_t)RSLOTS * NL * BATCH * HID;  // 524288 uints = 2 MB
  unsigned int* ring = (unsigned int*)d_ws;
  int* done = (int*)(ring + ringElems);   // ws is poisoned 0xAA -> must zero flags

  hipMemsetAsync(done, 0, (NL * NG) * FLSTR * sizeof(int), stream);
  rnn_wavefront<<<dim3(256), dim3(256), 0, stream>>>(x, Wih, Whh, bih, bhh, out,
                                                     ring, done);
}